// Round 5
// baseline (169.249 us; speedup 1.0000x reference)
//
#include <hip/hip_runtime.h>
#include <hip/hip_fp16.h>

typedef _Float16 f16x8  __attribute__((ext_vector_type(8)));
typedef _Float16 f16x4  __attribute__((ext_vector_type(4)));
typedef float    f32x16 __attribute__((ext_vector_type(16)));

constexpr int Nn = 8192;
constexpr int Dd = 256;

constexpr int BM = 64;     // I-rows per block
constexpr int KC = 1024;   // K range per block
constexpr int SK = 64;     // staged K subchunk; LDS buf = 256 n x 64 k f16 = 32 KB
constexpr int NSC = KC / SK;   // 16 subchunks

// ---------------------------------------------------------------------------
// K1: row sums of A -> dis[i] = rsqrt(sum+1e-10), rd[i] = sqrt(sum+1e-10)
//     also zeroes the T accumulator (ws is poisoned 0xAA before timing).
__global__ __launch_bounds__(256) void k_rowsum(const float* __restrict__ A,
                                                float* __restrict__ dis,
                                                float* __restrict__ rd,
                                                float* __restrict__ T) {
    if (blockIdx.x == 0 && threadIdx.x == 0) *T = 0.f;
    const int row  = blockIdx.x * 4 + (threadIdx.x >> 6);
    const int lane = threadIdx.x & 63;
    const float4* rp = reinterpret_cast<const float4*>(A + (size_t)row * Nn);
    float s = 0.f;
    #pragma unroll
    for (int i = 0; i < Nn / 256; ++i) {
        float4 v = rp[i * 64 + lane];
        s += (v.x + v.y) + (v.z + v.w);
    }
    #pragma unroll
    for (int off = 32; off > 0; off >>= 1) s += __shfl_down(s, off, 64);
    if (lane == 0) {
        float rs = s + 1e-10f;
        dis[row] = rsqrtf(rs);
        rd[row]  = sqrtf(rs);
    }
}

// ---------------------------------------------------------------------------
// K2: Y = dis * Z/||Z||; store Yt[256 n][8192 i] (k-major) and Yr[8192][256]
__global__ __launch_bounds__(256) void k_makeYt(const float* __restrict__ Z,
                                               const float* __restrict__ dis,
                                               _Float16* __restrict__ Yt,
                                               _Float16* __restrict__ Yr) {
    __shared__ float nrm[64][4];
    __shared__ _Float16 tile[Dd][72];
    const int t = threadIdx.x;
    const int r = t >> 2, q = t & 3;
    const int row = blockIdx.x * 64 + r;
    const float4* zp = reinterpret_cast<const float4*>(Z + (size_t)row * Dd + q * 64);
    float4 v[16];
    float ss = 0.f;
    #pragma unroll
    for (int i = 0; i < 16; ++i) {
        v[i] = zp[i];
        ss += v[i].x*v[i].x + v[i].y*v[i].y + v[i].z*v[i].z + v[i].w*v[i].w;
    }
    nrm[r][q] = ss;
    __syncthreads();
    const float tot   = nrm[r][0] + nrm[r][1] + nrm[r][2] + nrm[r][3];
    const float scale = dis[row] / fmaxf(sqrtf(tot), 1e-12f);
    #pragma unroll
    for (int i = 0; i < 16; ++i) {
        const int c0 = q * 64 + i * 4;
        f16x4 y = { (_Float16)(v[i].x * scale), (_Float16)(v[i].y * scale),
                    (_Float16)(v[i].z * scale), (_Float16)(v[i].w * scale) };
        tile[c0+0][r] = y[0];
        tile[c0+1][r] = y[1];
        tile[c0+2][r] = y[2];
        tile[c0+3][r] = y[3];
        *reinterpret_cast<f16x4*>(Yr + (size_t)row * Dd + c0) = y;
    }
    __syncthreads();
    int4*       dst = reinterpret_cast<int4*>(Yt + (size_t)t * Nn + blockIdx.x * 64);
    const int4* src = reinterpret_cast<const int4*>(&tile[t][0]);
    #pragma unroll
    for (int i = 0; i < 8; ++i) dst[i] = src[i];
}

// ---------------------------------------------------------------------------
// K2b: s[k] = sum_j Zn[j][k] = sum_j Yt[k][j] * rd[j]
__global__ __launch_bounds__(256) void k_colsum(const _Float16* __restrict__ Yt,
                                                const float* __restrict__ rd,
                                                float* __restrict__ s) {
    const int k = blockIdx.x;
    const int t = threadIdx.x;
    const _Float16* yp = Yt + (size_t)k * Nn + t * 32;
    const float*    rp = rd + t * 32;
    float acc = 0.f;
    #pragma unroll
    for (int i = 0; i < 32; ++i) acc += (float)yp[i] * rp[i];
    #pragma unroll
    for (int off = 32; off > 0; off >>= 1) acc += __shfl_down(acc, off, 64);
    __shared__ float red[4];
    if ((t & 63) == 0) red[t >> 6] = acc;
    __syncthreads();
    if (t == 0) s[k] = red[0] + red[1] + red[2] + red[3];
}

// ---------------------------------------------------------------------------
// K3: T += sum_{i in I-tile} Y_i . (A[I, Kchunk] @ Y[Kchunk])   [32x32x16 MFMA]
// Block mapping (THE round-5 change): jb = blockIdx&7 so that with round-robin
// XCD dispatch (xcd = blockIdx%8) each XCD stages only its own 512 KB K-slice
// of Yt -> L2-resident staging instead of thrashing L3. ib descending so
// k_main's A-reads start with the rows k_rowsum streamed into L3 last.
__global__ __launch_bounds__(512, 4) void k_main(const float* __restrict__ A,
                                                 const _Float16* __restrict__ Yt,
                                                 const _Float16* __restrict__ Yr,
                                                 float* __restrict__ T) {
    __shared__ _Float16 Ys[2 * Dd * SK];   // [buf][n=256][8 slots of 8 f16], XOR-swizzled

    const int jb = blockIdx.x & 7;                      // K-chunk == XCD slice
    const int ib = (Nn / BM - 1) - (blockIdx.x >> 3);   // I-tile, descending
    const int I0 = ib * BM;
    const int K0 = jb * KC;
    const int w   = threadIdx.x >> 6;  // 0..7
    const int wm  = w & 1;             // 32-row half
    const int wn  = (w >> 1) & 1;      // 128-col half
    const int wk  = w >> 2;            // 32-k half of subchunk
    const int l   = threadIdx.x & 63;
    const int ln  = l & 31;
    const int lkh = l >> 5;

    const size_t arow = (size_t)(I0 + wm * 32 + ln) * Nn;
    const int    koff = wk * 32 + lkh * 8;       // lane's k-offset within subchunk

    f32x16 acc[4];
    #pragma unroll
    for (int t = 0; t < 4; ++t) acc[t] = (f32x16)(0.f);

    // Stage one 32 KB subchunk into buffer BUF. Wave w covers rows
    // [w*32, w*32+32), 1 KB (8 rows) per q. Linear LDS dest; global source
    // slot pre-swizzled: LDS(n, t) holds global slot t^(n&7).
    #define STAGE(SC, BUF)                                                     \
    {   const int kc = K0 + (SC) * SK;                                         \
        _Pragma("unroll")                                                      \
        for (int q = 0; q < 4; ++q) {                                          \
            const int nrow = w * 32 + q * 8 + (l >> 3);                        \
            const int s8   = (l & 7) ^ (l >> 3);                               \
            __builtin_amdgcn_global_load_lds(                                  \
                (const __attribute__((address_space(1))) unsigned int*)        \
                    (Yt + (size_t)nrow * Nn + kc + s8 * 8),                    \
                (__attribute__((address_space(3))) unsigned int*)              \
                    (Ys + (BUF) * (Dd * SK) + (w * 32 + q * 8) * SK),          \
                16, 0, 0);                                                     \
        }                                                                      \
    }

    float4 av[4];
    #define LOADA(SC)                                                          \
    {   const float* ab = A + arow + K0 + (SC) * SK + koff;                    \
        av[0] = *reinterpret_cast<const float4*>(ab);                          \
        av[1] = *reinterpret_cast<const float4*>(ab + 4);                      \
        av[2] = *reinterpret_cast<const float4*>(ab + 16);                     \
        av[3] = *reinterpret_cast<const float4*>(ab + 20);                     \
    }

    STAGE(0, 0);
    LOADA(0);
    asm volatile("s_waitcnt vmcnt(0)" ::: "memory");
    __builtin_amdgcn_s_barrier();

    for (int sc = 0; sc < NSC; ++sc) {
        const int cur = sc & 1;
        f16x8 af[2];
        #pragma unroll
        for (int ks = 0; ks < 2; ++ks) {
            const float4 a0 = av[ks*2], a1 = av[ks*2+1];
            af[ks] = f16x8{ (_Float16)a0.x, (_Float16)a0.y, (_Float16)a0.z, (_Float16)a0.w,
                            (_Float16)a1.x, (_Float16)a1.y, (_Float16)a1.z, (_Float16)a1.w };
        }
        if (sc + 1 < NSC) {
            STAGE(sc + 1, cur ^ 1);     // 4 gload_lds in flight under MFMA
            LOADA(sc + 1);              // 4 A-loads in flight across barrier
        }
        #pragma unroll
        for (int tn = 0; tn < 4; ++tn) {
            const int n = wn * 128 + tn * 32 + ln;
            #pragma unroll
            for (int ks = 0; ks < 2; ++ks) {
                const int sl = (wk * 4 + ks * 2 + lkh) ^ (n & 7);
                const f16x8 bf = *reinterpret_cast<const f16x8*>(
                    Ys + cur * (Dd * SK) + n * SK + sl * 8);
                acc[tn] = __builtin_amdgcn_mfma_f32_32x32x16_f16(af[ks], bf, acc[tn], 0, 0, 0);
            }
        }
        if (sc + 1 < NSC) {
            // drain only the staging writes; the 4 A-loads stay outstanding
            asm volatile("s_waitcnt vmcnt(4)" ::: "memory");
            __builtin_amdgcn_s_barrier();
        }
    }

    // epilogue: part = sum over held W[i][n] * Y[i][n]
    float part = 0.f;
    #pragma unroll
    for (int tn = 0; tn < 4; ++tn) {
        const int n = wn * 128 + tn * 32 + ln;
        #pragma unroll
        for (int r = 0; r < 16; ++r) {
            const int i = I0 + wm * 32 + (r & 3) + 8 * (r >> 2) + 4 * lkh;
            part += acc[tn][r] * (float)Yr[(size_t)i * Dd + n];
        }
    }
    #pragma unroll
    for (int off = 32; off > 0; off >>= 1) part += __shfl_down(part, off, 64);
    __shared__ float red[8];
    if (l == 0) red[w] = part;
    __syncthreads();
    if (threadIdx.x == 0) {
        float t = 0.f;
        #pragma unroll
        for (int i = 0; i < 8; ++i) t += red[i];
        atomicAdd(T, t);
    }
}

// ---------------------------------------------------------------------------
// K4: out[0] = homo = -T ; out[1] = hetero = ||s||^2 - T
__global__ __launch_bounds__(256) void k_final(const float* __restrict__ s,
                                               const float* __restrict__ T,
                                               float* __restrict__ out) {
    const int t = threadIdx.x;
    float v = s[t];
    float p = v * v;
    #pragma unroll
    for (int off = 32; off > 0; off >>= 1) p += __shfl_down(p, off, 64);
    __shared__ float red[4];
    if ((t & 63) == 0) red[t >> 6] = p;
    __syncthreads();
    if (t == 0) {
        const float ss = red[0] + red[1] + red[2] + red[3];
        const float Tv = *T;
        out[0] = -Tv;
        out[1] = ss - Tv;
    }
}

// ---------------------------------------------------------------------------
extern "C" void kernel_launch(void* const* d_in, const int* in_sizes, int n_in,
                              void* d_out, int out_size, void* d_ws, size_t ws_size,
                              hipStream_t stream) {
    const float* Z = (const float*)d_in[1];
    const float* A = (const float*)d_in[2];
    float* out = (float*)d_out;

    char* ws = (char*)d_ws;
    float*    dis = (float*)(ws);                      // 32 KB
    float*    rd  = (float*)(ws + 32768);              // 32 KB
    float*    s   = (float*)(ws + 65536);              // 1 KB
    float*    T   = (float*)(ws + 66560);              // 4 B
    _Float16* Yt  = (_Float16*)(ws + 131072);          // 4 MB  [256][8192]
    _Float16* Yr  = (_Float16*)(ws + 131072 + (size_t)Nn * Dd * 2);  // 4 MB [8192][256]

    k_rowsum<<<Nn / 4, 256, 0, stream>>>(A, dis, rd, T);
    k_makeYt<<<Nn / 64, 256, 0, stream>>>(Z, dis, Yt, Yr);
    k_colsum<<<Dd, 256, 0, stream>>>(Yt, rd, s);
    k_main<<<(Nn / BM) * (Nn / KC), 512, 0, stream>>>(A, Yt, Yr, T);
    k_final<<<1, 256, 0, stream>>>(s, T, out);
}

// Round 6
// 136.166 us; speedup vs baseline: 1.2430x; 1.2430x over previous
//
#include <hip/hip_runtime.h>
#include <hip/hip_fp16.h>

typedef _Float16 f16x8  __attribute__((ext_vector_type(8)));
typedef _Float16 f16x4  __attribute__((ext_vector_type(4)));
typedef float    f32x16 __attribute__((ext_vector_type(16)));

constexpr int Nn = 8192;
constexpr int Dd = 256;

constexpr int BM = 256;    // I-rows per block (staging amortization: 512->128 MB)
constexpr int KC = 1024;   // K range per block
constexpr int SK = 64;     // staged K subchunk; LDS buf = 256 n x 64 k f16 = 32 KB
constexpr int NSC = KC / SK;   // 16 subchunks

// ---------------------------------------------------------------------------
// K1: row sums of A -> dis[i] = rsqrt(sum+1e-10), rd[i] = sqrt(sum+1e-10)
//     also zeroes the T accumulator (ws is poisoned 0xAA before timing).
__global__ __launch_bounds__(256) void k_rowsum(const float* __restrict__ A,
                                                float* __restrict__ dis,
                                                float* __restrict__ rd,
                                                float* __restrict__ T) {
    if (blockIdx.x == 0 && threadIdx.x == 0) *T = 0.f;
    const int row  = blockIdx.x * 4 + (threadIdx.x >> 6);
    const int lane = threadIdx.x & 63;
    const float4* rp = reinterpret_cast<const float4*>(A + (size_t)row * Nn);
    float s = 0.f;
    #pragma unroll
    for (int i = 0; i < Nn / 256; ++i) {
        float4 v = rp[i * 64 + lane];
        s += (v.x + v.y) + (v.z + v.w);
    }
    #pragma unroll
    for (int off = 32; off > 0; off >>= 1) s += __shfl_down(s, off, 64);
    if (lane == 0) {
        float rs = s + 1e-10f;
        dis[row] = rsqrtf(rs);
        rd[row]  = sqrtf(rs);
    }
}

// ---------------------------------------------------------------------------
// K2: Y = dis * Z/||Z||; store Yt[256 n][8192 i] (k-major) and Yr[8192][256]
__global__ __launch_bounds__(256) void k_makeYt(const float* __restrict__ Z,
                                               const float* __restrict__ dis,
                                               _Float16* __restrict__ Yt,
                                               _Float16* __restrict__ Yr) {
    __shared__ float nrm[64][4];
    __shared__ _Float16 tile[Dd][72];
    const int t = threadIdx.x;
    const int r = t >> 2, q = t & 3;
    const int row = blockIdx.x * 64 + r;
    const float4* zp = reinterpret_cast<const float4*>(Z + (size_t)row * Dd + q * 64);
    float4 v[16];
    float ss = 0.f;
    #pragma unroll
    for (int i = 0; i < 16; ++i) {
        v[i] = zp[i];
        ss += v[i].x*v[i].x + v[i].y*v[i].y + v[i].z*v[i].z + v[i].w*v[i].w;
    }
    nrm[r][q] = ss;
    __syncthreads();
    const float tot   = nrm[r][0] + nrm[r][1] + nrm[r][2] + nrm[r][3];
    const float scale = dis[row] / fmaxf(sqrtf(tot), 1e-12f);
    #pragma unroll
    for (int i = 0; i < 16; ++i) {
        const int c0 = q * 64 + i * 4;
        f16x4 y = { (_Float16)(v[i].x * scale), (_Float16)(v[i].y * scale),
                    (_Float16)(v[i].z * scale), (_Float16)(v[i].w * scale) };
        tile[c0+0][r] = y[0];
        tile[c0+1][r] = y[1];
        tile[c0+2][r] = y[2];
        tile[c0+3][r] = y[3];
        *reinterpret_cast<f16x4*>(Yr + (size_t)row * Dd + c0) = y;
    }
    __syncthreads();
    int4*       dst = reinterpret_cast<int4*>(Yt + (size_t)t * Nn + blockIdx.x * 64);
    const int4* src = reinterpret_cast<const int4*>(&tile[t][0]);
    #pragma unroll
    for (int i = 0; i < 8; ++i) dst[i] = src[i];
}

// ---------------------------------------------------------------------------
// K2b: s[k] = sum_j Zn[j][k] = sum_j Yt[k][j] * rd[j]
__global__ __launch_bounds__(256) void k_colsum(const _Float16* __restrict__ Yt,
                                                const float* __restrict__ rd,
                                                float* __restrict__ s) {
    const int k = blockIdx.x;
    const int t = threadIdx.x;
    const _Float16* yp = Yt + (size_t)k * Nn + t * 32;
    const float*    rp = rd + t * 32;
    float acc = 0.f;
    #pragma unroll
    for (int i = 0; i < 32; ++i) acc += (float)yp[i] * rp[i];
    #pragma unroll
    for (int off = 32; off > 0; off >>= 1) acc += __shfl_down(acc, off, 64);
    __shared__ float red[4];
    if ((t & 63) == 0) red[t >> 6] = acc;
    __syncthreads();
    if (t == 0) s[k] = red[0] + red[1] + red[2] + red[3];
}

// ---------------------------------------------------------------------------
// K3: T += sum_{i in I-tile} Y_i . (A[I, Kchunk] @ Y[Kchunk])   [32x32x16 MFMA]
// 1024 thr = 16 waves: wm = w>>1 (32-row stripe of 256), wn = w&1 (128-col
// half). Per wave: 4 n-tiles x 1 m-tile, acc = 4 x f32x16 = 64 VGPR.
// Subchunk compute split into two k-halves (h=0: k0-31, h=1: k32-63) so only
// 4 float4 A-regs are live at once (1024-thr blocks cap VGPR at 128).
// MFMA 32x32x16_f16: A row=l&31, k=(l>>5)*8+e; B col=l&31 same k;
// D col=l&31, row=(reg&3)+8*(reg>>2)+4*(l>>5).
__global__ __launch_bounds__(1024) void k_main(const float* __restrict__ A,
                                               const _Float16* __restrict__ Yt,
                                               const _Float16* __restrict__ Yr,
                                               float* __restrict__ T) {
    __shared__ _Float16 Ys[2 * Dd * SK];   // [buf][n=256][8 slots of 8 f16], XOR-swizzled

    const int ib = blockIdx.x & (Nn / BM - 1);   // 32 I-tiles (fastest -> round-4 map)
    const int jb = blockIdx.x >> 5;              // 8 K-chunks
    const int I0 = ib * BM;
    const int K0 = jb * KC;
    const int w   = threadIdx.x >> 6;  // 0..15
    const int wm  = w >> 1;            // 32-row stripe
    const int wn  = w & 1;             // 128-col half
    const int l   = threadIdx.x & 63;
    const int ln  = l & 31;
    const int lkh = l >> 5;

    const size_t arow = (size_t)(I0 + wm * 32 + ln) * Nn;

    f32x16 acc[4];
    #pragma unroll
    for (int t = 0; t < 4; ++t) acc[t] = (f32x16)(0.f);

    // Stage one 32 KB subchunk into buffer BUF. Wave w covers rows
    // [w*16, w*16+16), 1 KB (8 rows) per q. Linear LDS dest; global source
    // slot pre-swizzled: LDS(n, t) holds global slot t^(n&7).
    #define STAGE(SC, BUF)                                                     \
    {   const int kc = K0 + (SC) * SK;                                         \
        _Pragma("unroll")                                                      \
        for (int q = 0; q < 2; ++q) {                                          \
            const int nrow = w * 16 + q * 8 + (l >> 3);                        \
            const int s8   = (l & 7) ^ (l >> 3);                               \
            __builtin_amdgcn_global_load_lds(                                  \
                (const __attribute__((address_space(1))) unsigned int*)        \
                    (Yt + (size_t)nrow * Nn + kc + s8 * 8),                    \
                (__attribute__((address_space(3))) unsigned int*)              \
                    (Ys + (BUF) * (Dd * SK) + (w * 16 + q * 8) * SK),          \
                16, 0, 0);                                                     \
        }                                                                      \
    }

    float4 av[4];
    // load A for k-half H of subchunk SC: k in [H*32, H*32+32) per wave
    #define LOADA(SC, H)                                                       \
    {   const float* ab = A + arow + K0 + (SC) * SK + (H) * 32 + lkh * 8;      \
        av[0] = *reinterpret_cast<const float4*>(ab);                          \
        av[1] = *reinterpret_cast<const float4*>(ab + 4);                      \
        av[2] = *reinterpret_cast<const float4*>(ab + 16);                     \
        av[3] = *reinterpret_cast<const float4*>(ab + 20);                     \
    }

    #define CVT(AF)                                                            \
    {   const float4 a0 = av[0], a1 = av[1], a2 = av[2], a3 = av[3];           \
        AF[0] = f16x8{ (_Float16)a0.x, (_Float16)a0.y, (_Float16)a0.z,         \
                       (_Float16)a0.w, (_Float16)a1.x, (_Float16)a1.y,         \
                       (_Float16)a1.z, (_Float16)a1.w };                       \
        AF[1] = f16x8{ (_Float16)a2.x, (_Float16)a2.y, (_Float16)a2.z,         \
                       (_Float16)a2.w, (_Float16)a3.x, (_Float16)a3.y,         \
                       (_Float16)a3.z, (_Float16)a3.w };                       \
    }

    // MFMA one k-half H from buffer CUR using fragments AF
    #define HALF(CUR, H, AF)                                                   \
    {   _Pragma("unroll")                                                      \
        for (int tn = 0; tn < 4; ++tn) {                                       \
            const int n = wn * 128 + tn * 32 + ln;                             \
            _Pragma("unroll")                                                  \
            for (int ks = 0; ks < 2; ++ks) {                                   \
                const int sl = ((H) * 4 + ks * 2 + lkh) ^ (n & 7);             \
                const f16x8 bf = *reinterpret_cast<const f16x8*>(              \
                    Ys + (CUR) * (Dd * SK) + n * SK + sl * 8);                 \
                acc[tn] = __builtin_amdgcn_mfma_f32_32x32x16_f16(              \
                    AF[ks], bf, acc[tn], 0, 0, 0);                             \
            }                                                                  \
        }                                                                      \
    }

    STAGE(0, 0);
    LOADA(0, 0);
    asm volatile("s_waitcnt vmcnt(0)" ::: "memory");
    __builtin_amdgcn_s_barrier();

    for (int sc = 0; sc < NSC; ++sc) {
        const int cur = sc & 1;
        f16x8 af0[2], af1[2];
        CVT(af0);                       // waits av (h0)
        LOADA(sc, 1);                   // 4 in flight
        if (sc + 1 < NSC) STAGE(sc + 1, cur ^ 1);   // +2 -> 6
        HALF(cur, 0, af0);
        CVT(af1);                       // waits av (h1); stage stays in flight
        if (sc + 1 < NSC) LOADA(sc + 1, 0);         // +4 -> 6 (2 stage oldest)
        HALF(cur, 1, af1);
        if (sc + 1 < NSC) {
            asm volatile("s_waitcnt vmcnt(4)" ::: "memory");  // drain stage only
            __builtin_amdgcn_s_barrier();
        }
    }

    // epilogue: part = sum over held W[i][n] * Y[i][n]
    float part = 0.f;
    #pragma unroll
    for (int tn = 0; tn < 4; ++tn) {
        const int n = wn * 128 + tn * 32 + ln;
        #pragma unroll
        for (int r = 0; r < 16; ++r) {
            const int i = I0 + wm * 32 + (r & 3) + 8 * (r >> 2) + 4 * lkh;
            part += acc[tn][r] * (float)Yr[(size_t)i * Dd + n];
        }
    }
    #pragma unroll
    for (int off = 32; off > 0; off >>= 1) part += __shfl_down(part, off, 64);
    __shared__ float red[16];
    if (l == 0) red[w] = part;
    __syncthreads();
    if (threadIdx.x == 0) {
        float t = 0.f;
        #pragma unroll
        for (int i = 0; i < 16; ++i) t += red[i];
        atomicAdd(T, t);
    }
}

// ---------------------------------------------------------------------------
// K4: out[0] = homo = -T ; out[1] = hetero = ||s||^2 - T
__global__ __launch_bounds__(256) void k_final(const float* __restrict__ s,
                                               const float* __restrict__ T,
                                               float* __restrict__ out) {
    const int t = threadIdx.x;
    float v = s[t];
    float p = v * v;
    #pragma unroll
    for (int off = 32; off > 0; off >>= 1) p += __shfl_down(p, off, 64);
    __shared__ float red[4];
    if ((t & 63) == 0) red[t >> 6] = p;
    __syncthreads();
    if (t == 0) {
        const float ss = red[0] + red[1] + red[2] + red[3];
        const float Tv = *T;
        out[0] = -Tv;
        out[1] = ss - Tv;
    }
}

// ---------------------------------------------------------------------------
extern "C" void kernel_launch(void* const* d_in, const int* in_sizes, int n_in,
                              void* d_out, int out_size, void* d_ws, size_t ws_size,
                              hipStream_t stream) {
    const float* Z = (const float*)d_in[1];
    const float* A = (const float*)d_in[2];
    float* out = (float*)d_out;

    char* ws = (char*)d_ws;
    float*    dis = (float*)(ws);                      // 32 KB
    float*    rd  = (float*)(ws + 32768);              // 32 KB
    float*    s   = (float*)(ws + 65536);              // 1 KB
    float*    T   = (float*)(ws + 66560);              // 4 B
    _Float16* Yt  = (_Float16*)(ws + 131072);          // 4 MB  [256][8192]
    _Float16* Yr  = (_Float16*)(ws + 131072 + (size_t)Nn * Dd * 2);  // 4 MB [8192][256]

    k_rowsum<<<Nn / 4, 256, 0, stream>>>(A, dis, rd, T);
    k_makeYt<<<Nn / 64, 256, 0, stream>>>(Z, dis, Yt, Yr);
    k_colsum<<<Dd, 256, 0, stream>>>(Yt, rd, s);
    k_main<<<(Nn / BM) * (Nn / KC), 1024, 0, stream>>>(A, Yt, Yr, T);
    k_final<<<1, 256, 0, stream>>>(s, T, out);
}

// Round 7
// 126.637 us; speedup vs baseline: 1.3365x; 1.0752x over previous
//
#include <hip/hip_runtime.h>
#include <hip/hip_fp16.h>

typedef _Float16 f16x8  __attribute__((ext_vector_type(8)));
typedef _Float16 f16x4  __attribute__((ext_vector_type(4)));
typedef float    f32x16 __attribute__((ext_vector_type(16)));

constexpr int Nn = 8192;
constexpr int Dd = 256;

constexpr int BM = 256;        // I-rows per block
constexpr int KC = 1024;       // K range per block
constexpr int SK = 32;         // staged K subchunk
constexpr int NSC = KC / SK;   // 32 subchunks
constexpr int ABUF = BM * SK;  // 8192 f32  = 32 KB per buffer
constexpr int YBUF = Dd * SK;  // 8192 f16  = 16 KB per buffer

// ---------------------------------------------------------------------------
// K1: row sums of A -> dis[i] = rsqrt(sum+1e-10), rd[i] = sqrt(sum+1e-10)
//     also zeroes the T accumulator (ws is poisoned 0xAA before timing).
__global__ __launch_bounds__(256) void k_rowsum(const float* __restrict__ A,
                                                float* __restrict__ dis,
                                                float* __restrict__ rd,
                                                float* __restrict__ T) {
    if (blockIdx.x == 0 && threadIdx.x == 0) *T = 0.f;
    const int row  = blockIdx.x * 4 + (threadIdx.x >> 6);
    const int lane = threadIdx.x & 63;
    const float4* rp = reinterpret_cast<const float4*>(A + (size_t)row * Nn);
    float s = 0.f;
    #pragma unroll
    for (int i = 0; i < Nn / 256; ++i) {
        float4 v = rp[i * 64 + lane];
        s += (v.x + v.y) + (v.z + v.w);
    }
    #pragma unroll
    for (int off = 32; off > 0; off >>= 1) s += __shfl_down(s, off, 64);
    if (lane == 0) {
        float rs = s + 1e-10f;
        dis[row] = rsqrtf(rs);
        rd[row]  = sqrtf(rs);
    }
}

// ---------------------------------------------------------------------------
// K2: Y = dis * Z/||Z||; store Yt[256 n][8192 i] (k-major) and Yr[8192][256]
__global__ __launch_bounds__(256) void k_makeYt(const float* __restrict__ Z,
                                               const float* __restrict__ dis,
                                               _Float16* __restrict__ Yt,
                                               _Float16* __restrict__ Yr) {
    __shared__ float nrm[64][4];
    __shared__ _Float16 tile[Dd][72];
    const int t = threadIdx.x;
    const int r = t >> 2, q = t & 3;
    const int row = blockIdx.x * 64 + r;
    const float4* zp = reinterpret_cast<const float4*>(Z + (size_t)row * Dd + q * 64);
    float4 v[16];
    float ss = 0.f;
    #pragma unroll
    for (int i = 0; i < 16; ++i) {
        v[i] = zp[i];
        ss += v[i].x*v[i].x + v[i].y*v[i].y + v[i].z*v[i].z + v[i].w*v[i].w;
    }
    nrm[r][q] = ss;
    __syncthreads();
    const float tot   = nrm[r][0] + nrm[r][1] + nrm[r][2] + nrm[r][3];
    const float scale = dis[row] / fmaxf(sqrtf(tot), 1e-12f);
    #pragma unroll
    for (int i = 0; i < 16; ++i) {
        const int c0 = q * 64 + i * 4;
        f16x4 y = { (_Float16)(v[i].x * scale), (_Float16)(v[i].y * scale),
                    (_Float16)(v[i].z * scale), (_Float16)(v[i].w * scale) };
        tile[c0+0][r] = y[0];
        tile[c0+1][r] = y[1];
        tile[c0+2][r] = y[2];
        tile[c0+3][r] = y[3];
        *reinterpret_cast<f16x4*>(Yr + (size_t)row * Dd + c0) = y;
    }
    __syncthreads();
    int4*       dst = reinterpret_cast<int4*>(Yt + (size_t)t * Nn + blockIdx.x * 64);
    const int4* src = reinterpret_cast<const int4*>(&tile[t][0]);
    #pragma unroll
    for (int i = 0; i < 8; ++i) dst[i] = src[i];
}

// ---------------------------------------------------------------------------
// K2b: s[k] = sum_j Zn[j][k] = sum_j Yt[k][j] * rd[j]
__global__ __launch_bounds__(256) void k_colsum(const _Float16* __restrict__ Yt,
                                                const float* __restrict__ rd,
                                                float* __restrict__ s) {
    const int k = blockIdx.x;
    const int t = threadIdx.x;
    const _Float16* yp = Yt + (size_t)k * Nn + t * 32;
    const float*    rp = rd + t * 32;
    float acc = 0.f;
    #pragma unroll
    for (int i = 0; i < 32; ++i) acc += (float)yp[i] * rp[i];
    #pragma unroll
    for (int off = 32; off > 0; off >>= 1) acc += __shfl_down(acc, off, 64);
    __shared__ float red[4];
    if ((t & 63) == 0) red[t >> 6] = acc;
    __syncthreads();
    if (t == 0) s[k] = red[0] + red[1] + red[2] + red[3];
}

// ---------------------------------------------------------------------------
// K3: T += sum_{i} Y_i . (A[I, Kchunk] @ Y[Kchunk])   [32x32x16 MFMA]
// Round-7 change: A is ALSO staged via global_load_lds (fire-and-forget DMA,
// no VGPR dest) so ~48 KB/CU is always in flight -> HBM stays saturated
// (Little's law: need ~9 KB/CU at 900cyc latency; VGPR-held A gave only 2 KB).
// Triple-buffered LDS: 3 x (32 KB A + 16 KB Yt) = 144 KB. Per iteration:
// wait vmcnt(3) [current subchunk done, next still in flight], barrier,
// issue stage sc+2, compute sc. LDS swizzles: A slot^(row&7), Yt
// slot^((n>>1)&3) -- both hit the 8clk/b128 64-lane bank floor.
// MFMA 32x32x16_f16: A row=l&31, k=(l>>5)*8+e; B col=l&31 same k;
// D col=l&31, row=(reg&3)+8*(reg>>2)+4*(l>>5).
__global__ __launch_bounds__(1024, 4) void k_main(const float* __restrict__ A,
                                                  const _Float16* __restrict__ Yt,
                                                  const _Float16* __restrict__ Yr,
                                                  float* __restrict__ T) {
    __shared__ float    As[3 * ABUF];    // 96 KB
    __shared__ _Float16 Ysm[3 * YBUF];   // 48 KB

    const int ib = blockIdx.x & (Nn / BM - 1);   // 32 I-tiles (fastest)
    const int jb = blockIdx.x >> 5;              // 8 K-chunks
    const int I0 = ib * BM;
    const int K0 = jb * KC;
    const int t   = threadIdx.x;
    const int w   = t >> 6;            // 0..15
    const int wm  = w >> 1;            // 32-row stripe (0..7)
    const int wn  = w & 1;             // 128-col half
    const int l   = t & 63;
    const int ln  = l & 31;
    const int lkh = l >> 5;

    f32x16 acc[4];
    #pragma unroll
    for (int q = 0; q < 4; ++q) acc[q] = (f32x16)(0.f);

    // Stage subchunk SC into buffer B: 2 A-shots (16 KB each) + 1 Yt-shot.
    // Linear LDS dest (wave base + lane*16); source slot pre-swizzled.
    #define STAGE(SC, B)                                                       \
    {   const int kc = K0 + (SC) * SK;                                         \
        const int ga = (l & 7) ^ (l >> 3);                                     \
        _Pragma("unroll")                                                      \
        for (int q = 0; q < 2; ++q) {                                          \
            const int row = q * 128 + w * 8 + (l >> 3);                        \
            __builtin_amdgcn_global_load_lds(                                  \
                (const __attribute__((address_space(1))) unsigned int*)        \
                    (A + (size_t)(I0 + row) * Nn + kc + ga * 4),               \
                (__attribute__((address_space(3))) unsigned int*)              \
                    (As + (B) * ABUF + (q * 128 + w * 8) * SK),                \
                16, 0, 0);                                                     \
        }                                                                      \
        const int gy = (l & 3) ^ ((l >> 3) & 3);                               \
        const int nr = w * 16 + (l >> 2);                                      \
        __builtin_amdgcn_global_load_lds(                                      \
            (const __attribute__((address_space(1))) unsigned int*)            \
                (Yt + (size_t)nr * Nn + kc + gy * 8),                          \
            (__attribute__((address_space(3))) unsigned int*)                  \
                (Ysm + (B) * YBUF + (w * 16) * SK),                            \
            16, 0, 0);                                                         \
    }

    STAGE(0, 0);
    STAGE(1, 1);

    for (int sc = 0; sc < NSC; ++sc) {
        if (sc + 1 < NSC) { asm volatile("s_waitcnt vmcnt(3)" ::: "memory"); }
        else              { asm volatile("s_waitcnt vmcnt(0)" ::: "memory"); }
        __builtin_amdgcn_s_barrier();
        if (sc + 2 < NSC) {
            const int b2 = (sc + 2) % 3;
            STAGE(sc + 2, b2);
        }
        const int cb = sc % 3;
        const float*    Ab = As  + cb * ABUF + (wm * 32 + ln) * SK;
        const _Float16* Yb = Ysm + cb * YBUF;
        const int r7 = ln & 7;
        f16x8 af[2];
        #pragma unroll
        for (int ks = 0; ks < 2; ++ks) {
            const int s0 = ks * 4 + lkh * 2;
            const float4 u0 = *reinterpret_cast<const float4*>(Ab + ((s0)     ^ r7) * 4);
            const float4 u1 = *reinterpret_cast<const float4*>(Ab + ((s0 + 1) ^ r7) * 4);
            af[ks] = f16x8{ (_Float16)u0.x, (_Float16)u0.y, (_Float16)u0.z, (_Float16)u0.w,
                            (_Float16)u1.x, (_Float16)u1.y, (_Float16)u1.z, (_Float16)u1.w };
        }
        #pragma unroll
        for (int tn = 0; tn < 4; ++tn) {
            const int n = wn * 128 + tn * 32 + ln;
            const _Float16* Yrow = Yb + n * SK;
            const int sw = (ln >> 1) & 3;
            #pragma unroll
            for (int ks = 0; ks < 2; ++ks) {
                const int tt = (ks * 2 + lkh) ^ sw;
                const f16x8 bf = *reinterpret_cast<const f16x8*>(Yrow + tt * 8);
                acc[tn] = __builtin_amdgcn_mfma_f32_32x32x16_f16(af[ks], bf, acc[tn], 0, 0, 0);
            }
        }
    }

    // epilogue: part = sum over held W[i][n] * Y[i][n]
    float part = 0.f;
    #pragma unroll
    for (int tn = 0; tn < 4; ++tn) {
        const int n = wn * 128 + tn * 32 + ln;
        #pragma unroll
        for (int r = 0; r < 16; ++r) {
            const int i = I0 + wm * 32 + (r & 3) + 8 * (r >> 2) + 4 * lkh;
            part += acc[tn][r] * (float)Yr[(size_t)i * Dd + n];
        }
    }
    #pragma unroll
    for (int off = 32; off > 0; off >>= 1) part += __shfl_down(part, off, 64);
    __shared__ float red[16];
    if (l == 0) red[w] = part;
    __syncthreads();
    if (threadIdx.x == 0) {
        float tt = 0.f;
        #pragma unroll
        for (int i = 0; i < 16; ++i) tt += red[i];
        atomicAdd(T, tt);
    }
}

// ---------------------------------------------------------------------------
// K4: out[0] = homo = -T ; out[1] = hetero = ||s||^2 - T
__global__ __launch_bounds__(256) void k_final(const float* __restrict__ s,
                                               const float* __restrict__ T,
                                               float* __restrict__ out) {
    const int t = threadIdx.x;
    float v = s[t];
    float p = v * v;
    #pragma unroll
    for (int off = 32; off > 0; off >>= 1) p += __shfl_down(p, off, 64);
    __shared__ float red[4];
    if ((t & 63) == 0) red[t >> 6] = p;
    __syncthreads();
    if (t == 0) {
        const float ss = red[0] + red[1] + red[2] + red[3];
        const float Tv = *T;
        out[0] = -Tv;
        out[1] = ss - Tv;
    }
}

// ---------------------------------------------------------------------------
extern "C" void kernel_launch(void* const* d_in, const int* in_sizes, int n_in,
                              void* d_out, int out_size, void* d_ws, size_t ws_size,
                              hipStream_t stream) {
    const float* Z = (const float*)d_in[1];
    const float* A = (const float*)d_in[2];
    float* out = (float*)d_out;

    char* ws = (char*)d_ws;
    float*    dis = (float*)(ws);                      // 32 KB
    float*    rd  = (float*)(ws + 32768);              // 32 KB
    float*    s   = (float*)(ws + 65536);              // 1 KB
    float*    T   = (float*)(ws + 66560);              // 4 B
    _Float16* Yt  = (_Float16*)(ws + 131072);          // 4 MB  [256][8192]
    _Float16* Yr  = (_Float16*)(ws + 131072 + (size_t)Nn * Dd * 2);  // 4 MB [8192][256]

    k_rowsum<<<Nn / 4, 256, 0, stream>>>(A, dis, rd, T);
    k_makeYt<<<Nn / 64, 256, 0, stream>>>(Z, dis, Yt, Yr);
    k_colsum<<<Dd, 256, 0, stream>>>(Yt, rd, s);
    k_main<<<(Nn / BM) * (Nn / KC), 1024, 0, stream>>>(A, Yt, Yr, T);
    k_final<<<1, 256, 0, stream>>>(s, T, out);
}